// Round 14
// baseline (376.788 us; speedup 1.0000x reference)
//
#include <hip/hip_runtime.h>
#include <hip/hip_bf16.h>

// Problem constants
#define B_SZ   4
#define S_LEN  2048
#define E_DIM  1024
#define H_NUM  16
#define D_DIM  64
#define M_ROWS (B_SZ * S_LEN)            // 8192
#define QK_SCALE 0.1803368801111204f     // (1/sqrt(64)) * log2(e): softmax in exp2 domain

typedef __attribute__((ext_vector_type(8))) __bf16 bf16x8;
typedef __attribute__((ext_vector_type(4))) float  f32x4;

__device__ __forceinline__ bf16x8 load8(const void* p) {
    return __builtin_bit_cast(bf16x8, *reinterpret_cast<const uint4*>(p));
}

#if defined(__has_builtin)
#if __has_builtin(__builtin_amdgcn_exp2f)
#define EXP2F(x) __builtin_amdgcn_exp2f(x)
#endif
#if __has_builtin(__builtin_amdgcn_global_load_lds)
#define HAVE_GLL 1
#endif
#endif
#ifndef EXP2F
#define EXP2F(x) exp2f(x)
#endif

// 16B-per-lane global->LDS stage (wave-uniform LDS base, lane i -> base+16i).
__device__ __forceinline__ void stage16(const __hip_bfloat16* g, __hip_bfloat16* lbase, int lane) {
#ifdef HAVE_GLL
    __builtin_amdgcn_global_load_lds((const __attribute__((address_space(1))) unsigned int*)g,
                                     (__attribute__((address_space(3))) unsigned int*)lbase,
                                     16, 0, 0);
#else
    reinterpret_cast<uint4*>(lbase)[lane] = *reinterpret_cast<const uint4*>(g);
#endif
}

// ---------------------------------------------------------------------------
// Fused f32 -> bf16 convert for ALL 7 tensors in ONE dispatch (~33us).
// ---------------------------------------------------------------------------
#define N8A (1 << 20)
#define N8W (1 << 17)
#define N8TOT (3 * N8A + 4 * N8W)

struct CvtArgs {
    const float* s[7];
    __hip_bfloat16* d[7];
};

__global__ __launch_bounds__(256) void cvt_all(CvtArgs a)
{
    const int i = blockIdx.x * 256 + threadIdx.x;
    if (i >= N8TOT) return;
    int seg, off;
    if (i < 3 * N8A) { seg = i >> 20;              off = i & (N8A - 1); }
    else             { const int j = i - 3 * N8A;
                       seg = 3 + (j >> 17);        off = j & (N8W - 1); }
    const float* s = a.s[seg];
    __hip_bfloat16* d = a.d[seg];
    const float4 x = reinterpret_cast<const float4*>(s)[off * 2];
    const float4 y = reinterpret_cast<const float4*>(s)[off * 2 + 1];
    __hip_bfloat16 o[8];
    o[0] = __float2bfloat16(x.x); o[1] = __float2bfloat16(x.y);
    o[2] = __float2bfloat16(x.z); o[3] = __float2bfloat16(x.w);
    o[4] = __float2bfloat16(y.x); o[5] = __float2bfloat16(y.y);
    o[6] = __float2bfloat16(y.z); o[7] = __float2bfloat16(y.w);
    reinterpret_cast<uint4*>(d)[off] = *reinterpret_cast<uint4*>(o);
}

// single-tensor cvt kept for the fallback path
__global__ __launch_bounds__(256) void cvt_f32_bf16(const float* __restrict__ s,
                                                    __hip_bfloat16* __restrict__ d,
                                                    int n8)
{
    const int i = blockIdx.x * 256 + threadIdx.x;
    if (i >= n8) return;
    const float4 a = reinterpret_cast<const float4*>(s)[i * 2];
    const float4 b = reinterpret_cast<const float4*>(s)[i * 2 + 1];
    __hip_bfloat16 o[8];
    o[0] = __float2bfloat16(a.x); o[1] = __float2bfloat16(a.y);
    o[2] = __float2bfloat16(a.z); o[3] = __float2bfloat16(a.w);
    o[4] = __float2bfloat16(b.x); o[5] = __float2bfloat16(b.y);
    o[6] = __float2bfloat16(b.z); o[7] = __float2bfloat16(b.w);
    reinterpret_cast<uint4*>(d)[i] = *reinterpret_cast<uint4*>(o);
}

// ---------------------------------------------------------------------------
// Pipelined GEMM (R5/R7-measured, verbatim): C = A @ W^T + bias.
// BM=128, BN=256, BK=32, K=1024.  512 threads = 8 waves, 64x64 out/wave.
// 3-buffer LDS ring (72KB) -> 2 blocks/CU; prefetch distance 2; vmcnt(3).
// QKV: 768 blocks (~76us).  OG: 256 blocks (~48us).
// ---------------------------------------------------------------------------
struct GemmArgs {
    const __hip_bfloat16* A[3];
    const __hip_bfloat16* W[3];
    const float* bias[3];
    void* C[3];
    float scale[3];
    int mode[3];
};

__global__ __launch_bounds__(512, 4) void gemm_bt(GemmArgs g)
{
    __shared__ __attribute__((aligned(16))) char lds_raw[3 * 24576];   // 72 KB ring

    const int tid = threadIdx.x;
    const int wid = tid >> 6, lane = tid & 63;
    const int quad = lane >> 4, l16 = lane & 15;
    const int wm = wid >> 2, wn = wid & 3;

    const int seg = blockIdx.x >> 8;
    int bid = blockIdx.x & 255;
    bid = (bid & 7) * 32 + (bid >> 3);          // XCD-aware swizzle (bijective, 256 wg)
    const int bm = bid >> 2, bn = bid & 3;      // 64 x 4 tiles of 128x256
    const int row0 = bm * 128, col0 = bn * 256;

    const __hip_bfloat16* A = g.A[seg];
    const __hip_bfloat16* W = g.W[seg];

    // --- staging source mapping (linear LDS dest, inverse-swizzled source) ---
    const int s_line = tid >> 3, s_gr = tid & 7;
    const int glin  = s_gr ^ (s_line & 7);
    const int s_row = (s_line << 1) + (glin >> 2);
    const int s_ks  = glin & 3;
    const __hip_bfloat16* gA = A + (size_t)(row0 + s_row) * E_DIM + s_ks * 8;
    const __hip_bfloat16* gB = W + (size_t)(col0 + s_row) * E_DIM + s_ks * 8;
    const int stA = wid << 10;                  // wave-uniform LDS byte offset

    // --- swizzled ds_read byte offsets (per lane), +i*1024 per 16-row frag ---
    const int rg   = (((l16 & 1) << 2) | quad) ^ ((l16 >> 1) & 7);
    const int aoff = (wm * 32 + (l16 >> 1)) * 128 + rg * 16;
    const int boff = (wn * 32 + (l16 >> 1)) * 128 + rg * 16;

    f32x4 acc[4][4];
    const f32x4 zero = {0.f, 0.f, 0.f, 0.f};
#pragma unroll
    for (int i = 0; i < 4; i++)
#pragma unroll
        for (int j = 0; j < 4; j++) acc[i][j] = zero;

    auto stage_t = [&](int t) {
        char* b = lds_raw + (t % 3) * 24576;
        const int ko = t * 32;
        stage16(gA + ko, (__hip_bfloat16*)(b + stA), lane);                          // A 8KB
        stage16(gB + ko, (__hip_bfloat16*)(b + 8192 + stA), lane);                   // B lo
        stage16(gB + (size_t)128 * E_DIM + ko, (__hip_bfloat16*)(b + 16384 + stA), lane); // B hi
    };

    auto body = [&](int t, bool stg) {
        __builtin_amdgcn_s_barrier();
        __builtin_amdgcn_sched_barrier(0);
        if (stg) stage_t(t + 2);
        const char* ab = lds_raw + (t % 3) * 24576;
        bf16x8 af[4], bf[4];
#pragma unroll
        for (int i = 0; i < 4; i++) af[i] = load8(ab + aoff + i * 1024);
#pragma unroll
        for (int j = 0; j < 4; j++) bf[j] = load8(ab + 8192 + boff + j * 1024);
        __builtin_amdgcn_s_setprio(1);
#pragma unroll
        for (int i = 0; i < 4; i++)
#pragma unroll
            for (int j = 0; j < 4; j++)
                acc[i][j] = __builtin_amdgcn_mfma_f32_16x16x32_bf16(af[i], bf[j], acc[i][j], 0, 0, 0);
        __builtin_amdgcn_s_setprio(0);
        __builtin_amdgcn_sched_barrier(0);
    };

    const int NT = E_DIM / 32;                  // 32 K-tiles
    stage_t(0); stage_t(1);
    for (int t = 0; t < NT - 2; ++t) {
        asm volatile("s_waitcnt vmcnt(3)" ::: "memory");   // tile t's 3 loads landed
        body(t, true);
    }
    asm volatile("s_waitcnt vmcnt(3)" ::: "memory"); body(NT - 2, false);
    asm volatile("s_waitcnt vmcnt(0)" ::: "memory"); body(NT - 1, false);

    // ---- epilogue ----
    const int   mode  = g.mode[seg];
    const float scale = g.scale[seg];
    const float* bias = g.bias[seg];
    void* Cout        = g.C[seg];
#pragma unroll
    for (int j = 0; j < 4; j++) {
        const int col = col0 + wn * 64 + j * 16 + l16;
        const float bv = bias[col];
#pragma unroll
        for (int i = 0; i < 4; i++) {
            const int row = row0 + wm * 64 + i * 16 + quad * 4;
            if (mode == 3) {
                __attribute__((aligned(8))) __hip_bfloat16 o[4];
#pragma unroll
                for (int r = 0; r < 4; r++) o[r] = __float2bfloat16((acc[i][j][r] + bv) * scale);
                const int b_ = row >> 11, s_ = row & 2047, h_ = col >> 6, d_ = col & 63;
                *reinterpret_cast<uint2*>((__hip_bfloat16*)Cout +
                    (((size_t)(b_ * H_NUM + h_)) << 17) + (d_ << 11) + s_) =
                    *reinterpret_cast<uint2*>(o);
            } else {
#pragma unroll
                for (int r = 0; r < 4; r++) {
                    const float v = (acc[i][j][r] + bv) * scale;
                    const int rr = row + r;
                    if (mode == 0) {
                        ((__hip_bfloat16*)Cout)[(size_t)rr * E_DIM + col] = __float2bfloat16(v);
                    } else if (mode == 1) {
                        ((float*)Cout)[(size_t)rr * E_DIM + col] = v;
                    } else {
                        const int b_ = rr >> 11, s_ = rr & 2047, h_ = col >> 6, d_ = col & 63;
                        ((__hip_bfloat16*)Cout)[(((size_t)(b_ * H_NUM + h_)) << 17) + (s_ << 6) + d_] =
                            __float2bfloat16(v);
                    }
                }
            }
        }
    }
}

// ---------------------------------------------------------------------------
// Flash attention v5b: identical to v5 (R12/R13) except the s_setprio wrapper
// around the PV cluster is REMOVED — the shfl(ds_bpermute)-inside-raised-prio
// interaction was the only construct new to this kernel vs all green rounds;
// removing it rules out that hazard while preserving the experiment.
//   - P LDS round-trip replaced by in-register cross-quad __shfl (mapping
//     byte-verified vs the old Pls path for all (quad,j)).
//   - Pls eliminated: LDS 56KB -> 16KB -> 2 independent blocks/CU.
// Staging, swizzles, no-max exp2 softmax, epilogue: R7-verified, unchanged.
// ---------------------------------------------------------------------------
__global__ __launch_bounds__(256) void attn(const __hip_bfloat16* __restrict__ Qt,
                                            const __hip_bfloat16* __restrict__ Kt,
                                            const __hip_bfloat16* __restrict__ Vt,
                                            __hip_bfloat16* __restrict__ Op)
{
    __shared__ __attribute__((aligned(16))) __hip_bfloat16 Kls[2][32 * 64];     //  8 KB
    __shared__ __attribute__((aligned(16))) __hip_bfloat16 Vls[2][64 * 32];     //  8 KB

    const int x = blockIdx.x;                   // 512 blocks
    const int xcd = x & 7, idx = x >> 3;        // dispatch: block x -> XCD x%8
    const int bh     = xcd * 8 + (idx & 7);     // all 8 q-chunks of bh on one XCD
    const int qchunk = idx >> 3;                // 0..7, 256 q-rows each
    const int tid = threadIdx.x;
    const int wave = tid >> 6, lane = tid & 63;
    const int quad = lane >> 4, l16 = lane & 15;
    const int qrow0 = qchunk * 256 + wave * 64;

    const __hip_bfloat16* qb = Qt + ((size_t)bh << 17);
    const __hip_bfloat16* kb = Kt + ((size_t)bh << 17);
    const __hip_bfloat16* vb = Vt + ((size_t)bh << 17);

    // ---- staging source mapping (pre-swizzled global addresses, R7) ----
    const int skey = tid >> 3, sgk = (tid & 7) ^ (skey & 7);
    const __hip_bfloat16* kSrc = kb + (skey << 6) + (sgk << 3);
    const int sd = tid >> 2, sgv = (tid & 3) ^ ((sd >> 1) & 3);
    const __hip_bfloat16* vSrc = vb + ((size_t)sd << 11) + (sgv << 3);
    const int stW = wave << 10;                 // per-wave 1KB slice of each 4KB tile

    // swizzle keys for the read side
    const int ksw = l16 & 7, vsw = (l16 >> 1) & 3;

    // P-shfl source lanes: s0 = 2*(quad&1), s1 = s0+1 (at same l16)
    const int s0l = ((quad & 1) << 5) + l16;    // (2*(quad&1))*16 + l16
    const int s1l = s0l + 16;

    // Q fragments: 4 q-tiles x 2 d-halves (B-operand layout), held all kernel.
    bf16x8 qf[4][2];
#pragma unroll
    for (int qt = 0; qt < 4; qt++) {
        qf[qt][0] = load8(qb + ((qrow0 + qt * 16 + l16) << 6) + quad * 8);
        qf[qt][1] = load8(qb + ((qrow0 + qt * 16 + l16) << 6) + 32 + quad * 8);
    }

    const f32x4 zero = {0.f, 0.f, 0.f, 0.f};
    f32x4 o_acc[4][4];
#pragma unroll
    for (int qt = 0; qt < 4; qt++)
#pragma unroll
        for (int dj = 0; dj < 4; dj++) o_acc[qt][dj] = zero;
    float lsum[4] = {0.f, 0.f, 0.f, 0.f};

    auto stageKV = [&](int kv, int b) {
        stage16(kSrc + (kv << 6), (__hip_bfloat16*)((char*)&Kls[b][0] + stW), lane);
        stage16(vSrc + kv,        (__hip_bfloat16*)((char*)&Vls[b][0] + stW), lane);
    };

    auto compute = [&](int b) {
        const char* Kbuf = (const char*)&Kls[b][0];
        const char* Vbuf = (const char*)&Vls[b][0];
        uint2 w0[4], w1[4];                     // P rows in registers (static idx)
        // ---- S^T = K·Q^T for 2 key-tiles; p = exp2(s); pack to regs ----
#pragma unroll
        for (int t = 0; t < 2; t++) {
            const bf16x8 ka = load8(Kbuf + ((t * 16 + l16) << 7) + ((quad ^ ksw) << 4));
            const bf16x8 kc = load8(Kbuf + ((t * 16 + l16) << 7) + (((quad + 4) ^ ksw) << 4));
#pragma unroll
            for (int qt = 0; qt < 4; qt++) {
                f32x4 st = __builtin_amdgcn_mfma_f32_16x16x32_bf16(ka, qf[qt][0], zero, 0, 0, 0);
                st       = __builtin_amdgcn_mfma_f32_16x16x32_bf16(kc, qf[qt][1], st, 0, 0, 0);
                const float p0 = EXP2F(st[0]), p1 = EXP2F(st[1]);
                const float p2 = EXP2F(st[2]), p3 = EXP2F(st[3]);
                lsum[qt] += (p0 + p1) + (p2 + p3);
                const unsigned u0 = (unsigned)__bfloat16_as_ushort(__float2bfloat16(p0));
                const unsigned u1 = (unsigned)__bfloat16_as_ushort(__float2bfloat16(p1));
                const unsigned u2 = (unsigned)__bfloat16_as_ushort(__float2bfloat16(p2));
                const unsigned u3 = (unsigned)__bfloat16_as_ushort(__float2bfloat16(p3));
                uint2 w;
                w.x = (u1 << 16) | u0;
                w.y = (u3 << 16) | u2;
                if (t == 0) w0[qt] = w; else w1[qt] = w;
            }
        }
        // ---- O += P·V : pa built via cross-quad shfl (no LDS, no setprio) ----
        bf16x8 vf[4];
#pragma unroll
        for (int dj = 0; dj < 4; dj++)
            vf[dj] = load8(Vbuf + ((dj * 16 + l16) << 6) + ((quad ^ vsw) << 4));
#pragma unroll
        for (int qt = 0; qt < 4; qt++) {
            const int a0 = __shfl((int)w0[qt].x, s0l, 64);
            const int a1 = __shfl((int)w0[qt].y, s0l, 64);
            const int a2 = __shfl((int)w0[qt].x, s1l, 64);
            const int a3 = __shfl((int)w0[qt].y, s1l, 64);
            const int b0 = __shfl((int)w1[qt].x, s0l, 64);
            const int b1 = __shfl((int)w1[qt].y, s0l, 64);
            const int b2 = __shfl((int)w1[qt].x, s1l, 64);
            const int b3 = __shfl((int)w1[qt].y, s1l, 64);
            uint4 pd;
            pd.x = (unsigned)(quad < 2 ? a0 : b0);
            pd.y = (unsigned)(quad < 2 ? a1 : b1);
            pd.z = (unsigned)(quad < 2 ? a2 : b2);
            pd.w = (unsigned)(quad < 2 ? a3 : b3);
            const bf16x8 pa = __builtin_bit_cast(bf16x8, pd);
#pragma unroll
            for (int dj = 0; dj < 4; dj++)
                o_acc[qt][dj] = __builtin_amdgcn_mfma_f32_16x16x32_bf16(pa, vf[dj], o_acc[qt][dj], 0, 0, 0);
        }
    };

    stageKV(0, 0);
    int cur = 0;
    for (int kv0 = 0; kv0 < S_LEN; kv0 += 32) {
        __syncthreads();                        // staged buf[cur] landed; prev reads done
        if (kv0 + 32 < S_LEN) stageKV(kv0 + 32, cur ^ 1);
        compute(cur);
        cur ^= 1;
    }

    // ---- epilogue: reduce l across quads, redistribute to C-layout rows ----
    const int b_ = bh >> 4, h_ = bh & 15;
#pragma unroll
    for (int qt = 0; qt < 4; qt++) {
        float l = lsum[qt];
        l += __shfl_xor(l, 16, 64);
        l += __shfl_xor(l, 32, 64);
#pragma unroll
        for (int r = 0; r < 4; r++) {
            const float lr = __shfl(l, quad * 4 + r, 64);   // l of q-row qt*16+quad*4+r
            const float inv = 1.f / lr;
            const size_t ro = ((size_t)b_ * S_LEN + (qrow0 + qt * 16 + quad * 4 + r)) * E_DIM + h_ * D_DIM;
#pragma unroll
            for (int dj = 0; dj < 4; dj++)
                Op[ro + dj * 16 + l16] = __float2bfloat16(o_acc[qt][dj][r] * inv);
        }
    }
}

// ---------------------------------------------------------------------------
extern "C" void kernel_launch(void* const* d_in, const int* in_sizes, int n_in,
                              void* d_out, int out_size, void* d_ws, size_t ws_size,
                              hipStream_t stream)
{
    const float* Qf  = (const float*)d_in[0];
    const float* Kf  = (const float*)d_in[1];
    const float* Vf  = (const float*)d_in[2];
    const float* Wqf = (const float*)d_in[3];
    const float* bqf = (const float*)d_in[4];
    const float* Wkf = (const float*)d_in[5];
    const float* bkf = (const float*)d_in[6];
    const float* Wvf = (const float*)d_in[7];
    const float* bvf = (const float*)d_in[8];
    const float* Wof = (const float*)d_in[9];
    const float* bof = (const float*)d_in[10];

    const size_t n_act = (size_t)M_ROWS * E_DIM;   // 8,388,608
    const size_t n_w   = (size_t)E_DIM * E_DIM;    // 1,048,576

    const dim3 blk(256), gblk(512), ablk(256);
    const int cg_act = (int)(n_act / 8 / 256);
    const int cg_w   = (int)(n_w / 8 / 256);

    const size_t need_fast = (6 * n_act + 4 * n_w) * sizeof(__hip_bfloat16);  // 104 MB

    if (ws_size >= need_fast) {
        // ---- fast path: 4 dispatches total ----
        __hip_bfloat16* Xq = (__hip_bfloat16*)d_ws;
        __hip_bfloat16* Xk = Xq + n_act;
        __hip_bfloat16* Xv = Xk + n_act;
        __hip_bfloat16* Wb = Xv + n_act;           // 4 weights back-to-back
        __hip_bfloat16* Qt = Wb + 4 * n_w;
        __hip_bfloat16* Kt = Qt + n_act;
        __hip_bfloat16* Vt = Kt + n_act;

        // 1) all conversions in one launch (~33us)
        CvtArgs ca;
        ca.s[0] = Qf;  ca.s[1] = Kf;  ca.s[2] = Vf;
        ca.s[3] = Wqf; ca.s[4] = Wkf; ca.s[5] = Wvf; ca.s[6] = Wof;
        ca.d[0] = Xq;  ca.d[1] = Xk;  ca.d[2] = Xv;
        ca.d[3] = Wb;  ca.d[4] = Wb + n_w; ca.d[5] = Wb + 2 * n_w; ca.d[6] = Wb + 3 * n_w;
        cvt_all<<<dim3(N8TOT / 256), blk, 0, stream>>>(ca);

        // 2) QKV projections co-launched (R7-measured ~76us)
        GemmArgs qkv;
        qkv.A[0] = Xq;  qkv.A[1] = Xk;  qkv.A[2] = Xv;
        qkv.W[0] = Wb;  qkv.W[1] = Wb + n_w;  qkv.W[2] = Wb + 2*n_w;
        qkv.bias[0] = bqf;  qkv.bias[1] = bkf;  qkv.bias[2] = bvf;
        qkv.C[0] = Qt;  qkv.C[1] = Kt;  qkv.C[2] = Vt;
        qkv.scale[0] = QK_SCALE;  qkv.scale[1] = 1.0f;  qkv.scale[2] = 1.0f;
        qkv.mode[0] = 2;  qkv.mode[1] = 2;  qkv.mode[2] = 3;
        gemm_bt<<<dim3(768), gblk, 0, stream>>>(qkv);

        // 3) attention -> Xq (v5b: in-register P via shfl, 2 blocks/CU)
        attn<<<dim3(512), ablk, 0, stream>>>(Qt, Kt, Vt, Xq);

        // 4) output projection (R5/R7-measured ~48us)
        GemmArgs og;
        og.A[0] = Xq;  og.A[1] = Xq;  og.A[2] = Xq;
        og.W[0] = Wb + 3*n_w;  og.W[1] = og.W[0];  og.W[2] = og.W[0];
        og.bias[0] = bof;  og.bias[1] = bof;  og.bias[2] = bof;
        og.C[0] = d_out;  og.C[1] = d_out;  og.C[2] = d_out;
        og.scale[0] = 1.0f;  og.scale[1] = 1.0f;  og.scale[2] = 1.0f;
        og.mode[0] = 1;  og.mode[1] = 1;  og.mode[2] = 1;
        gemm_bt<<<dim3(256), gblk, 0, stream>>>(og);
    } else {
        // ---- fallback: sequential, shared X/Wb buffers (66 MB) ----
        __hip_bfloat16* X  = (__hip_bfloat16*)d_ws;
        __hip_bfloat16* Wb = X + n_act;
        __hip_bfloat16* Qt = Wb + n_w;
        __hip_bfloat16* Kt = Qt + n_act;
        __hip_bfloat16* Vt = Kt + n_act;

        auto one = [&](const float* Af, const float* Wf, const float* bf_,
                       void* C, float sc, int md) {
            cvt_f32_bf16<<<cg_act, blk, 0, stream>>>(Af, X, (int)(n_act / 8));
            cvt_f32_bf16<<<cg_w,   blk, 0, stream>>>(Wf, Wb, (int)(n_w / 8));
            GemmArgs a;
            a.A[0] = X; a.A[1] = X; a.A[2] = X;
            a.W[0] = Wb; a.W[1] = Wb; a.W[2] = Wb;
            a.bias[0] = bf_; a.bias[1] = bf_; a.bias[2] = bf_;
            a.C[0] = C; a.C[1] = C; a.C[2] = C;
            a.scale[0] = sc; a.scale[1] = sc; a.scale[2] = sc;
            a.mode[0] = md; a.mode[1] = md; a.mode[2] = md;
            gemm_bt<<<dim3(256), gblk, 0, stream>>>(a);
        };
        one(Qf, Wqf, bqf, Qt, QK_SCALE, 2);
        one(Kf, Wkf, bkf, Kt, 1.0f, 2);
        one(Vf, Wvf, bvf, Vt, 1.0f, 3);
        attn<<<dim3(512), ablk, 0, stream>>>(Qt, Kt, Vt, X);
        cvt_f32_bf16<<<cg_w, blk, 0, stream>>>(Wof, Wb, (int)(n_w / 8));
        GemmArgs og;
        og.A[0] = X; og.A[1] = X; og.A[2] = X;
        og.W[0] = Wb; og.W[1] = Wb; og.W[2] = Wb;
        og.bias[0] = bof; og.bias[1] = bof; og.bias[2] = bof;
        og.C[0] = d_out; og.C[1] = d_out; og.C[2] = d_out;
        og.scale[0] = 1.0f; og.scale[1] = 1.0f; og.scale[2] = 1.0f;
        og.mode[0] = 1; og.mode[1] = 1; og.mode[2] = 1;
        gemm_bt<<<dim3(256), gblk, 0, stream>>>(og);
    }
}

// Round 15
// 368.123 us; speedup vs baseline: 1.0235x; 1.0235x over previous
//
#include <hip/hip_runtime.h>
#include <hip/hip_bf16.h>

// Problem constants
#define B_SZ   4
#define S_LEN  2048
#define E_DIM  1024
#define H_NUM  16
#define D_DIM  64
#define M_ROWS (B_SZ * S_LEN)            // 8192
#define QK_SCALE 0.1803368801111204f     // (1/sqrt(64)) * log2(e): softmax in exp2 domain

typedef __attribute__((ext_vector_type(8))) __bf16 bf16x8;
typedef __attribute__((ext_vector_type(4))) float  f32x4;

__device__ __forceinline__ bf16x8 load8(const void* p) {
    return __builtin_bit_cast(bf16x8, *reinterpret_cast<const uint4*>(p));
}

#if defined(__has_builtin)
#if __has_builtin(__builtin_amdgcn_exp2f)
#define EXP2F(x) __builtin_amdgcn_exp2f(x)
#endif
#if __has_builtin(__builtin_amdgcn_global_load_lds)
#define HAVE_GLL 1
#endif
#endif
#ifndef EXP2F
#define EXP2F(x) exp2f(x)
#endif

// 16B-per-lane global->LDS stage (wave-uniform LDS base, lane i -> base+16i).
__device__ __forceinline__ void stage16(const __hip_bfloat16* g, __hip_bfloat16* lbase, int lane) {
#ifdef HAVE_GLL
    __builtin_amdgcn_global_load_lds((const __attribute__((address_space(1))) unsigned int*)g,
                                     (__attribute__((address_space(3))) unsigned int*)lbase,
                                     16, 0, 0);
#else
    reinterpret_cast<uint4*>(lbase)[lane] = *reinterpret_cast<const uint4*>(g);
#endif
}

// ---------------------------------------------------------------------------
// Fused f32 -> bf16 convert for ALL 7 tensors in ONE dispatch (~33us).
// ---------------------------------------------------------------------------
#define N8A (1 << 20)
#define N8W (1 << 17)
#define N8TOT (3 * N8A + 4 * N8W)

struct CvtArgs {
    const float* s[7];
    __hip_bfloat16* d[7];
};

__global__ __launch_bounds__(256) void cvt_all(CvtArgs a)
{
    const int i = blockIdx.x * 256 + threadIdx.x;
    if (i >= N8TOT) return;
    int seg, off;
    if (i < 3 * N8A) { seg = i >> 20;              off = i & (N8A - 1); }
    else             { const int j = i - 3 * N8A;
                       seg = 3 + (j >> 17);        off = j & (N8W - 1); }
    const float* s = a.s[seg];
    __hip_bfloat16* d = a.d[seg];
    const float4 x = reinterpret_cast<const float4*>(s)[off * 2];
    const float4 y = reinterpret_cast<const float4*>(s)[off * 2 + 1];
    __hip_bfloat16 o[8];
    o[0] = __float2bfloat16(x.x); o[1] = __float2bfloat16(x.y);
    o[2] = __float2bfloat16(x.z); o[3] = __float2bfloat16(x.w);
    o[4] = __float2bfloat16(y.x); o[5] = __float2bfloat16(y.y);
    o[6] = __float2bfloat16(y.z); o[7] = __float2bfloat16(y.w);
    reinterpret_cast<uint4*>(d)[off] = *reinterpret_cast<uint4*>(o);
}

// single-tensor cvt kept for the fallback path
__global__ __launch_bounds__(256) void cvt_f32_bf16(const float* __restrict__ s,
                                                    __hip_bfloat16* __restrict__ d,
                                                    int n8)
{
    const int i = blockIdx.x * 256 + threadIdx.x;
    if (i >= n8) return;
    const float4 a = reinterpret_cast<const float4*>(s)[i * 2];
    const float4 b = reinterpret_cast<const float4*>(s)[i * 2 + 1];
    __hip_bfloat16 o[8];
    o[0] = __float2bfloat16(a.x); o[1] = __float2bfloat16(a.y);
    o[2] = __float2bfloat16(a.z); o[3] = __float2bfloat16(a.w);
    o[4] = __float2bfloat16(b.x); o[5] = __float2bfloat16(b.y);
    o[6] = __float2bfloat16(b.z); o[7] = __float2bfloat16(b.w);
    reinterpret_cast<uint4*>(d)[i] = *reinterpret_cast<uint4*>(o);
}

// ---------------------------------------------------------------------------
// Pipelined GEMM (R5/R7/R11-measured, verbatim): C = A @ W^T + bias.
// BM=128, BN=256, BK=32, K=1024.  512 threads = 8 waves, 64x64 out/wave.
// 3-buffer LDS ring (72KB) -> 2 blocks/CU; prefetch distance 2; vmcnt(3).
// QKV: 768 blocks (~76us).  OG: 256 blocks (~48us).
// ---------------------------------------------------------------------------
struct GemmArgs {
    const __hip_bfloat16* A[3];
    const __hip_bfloat16* W[3];
    const float* bias[3];
    void* C[3];
    float scale[3];
    int mode[3];
};

__global__ __launch_bounds__(512, 4) void gemm_bt(GemmArgs g)
{
    __shared__ __attribute__((aligned(16))) char lds_raw[3 * 24576];   // 72 KB ring

    const int tid = threadIdx.x;
    const int wid = tid >> 6, lane = tid & 63;
    const int quad = lane >> 4, l16 = lane & 15;
    const int wm = wid >> 2, wn = wid & 3;

    const int seg = blockIdx.x >> 8;
    int bid = blockIdx.x & 255;
    bid = (bid & 7) * 32 + (bid >> 3);          // XCD-aware swizzle (bijective, 256 wg)
    const int bm = bid >> 2, bn = bid & 3;      // 64 x 4 tiles of 128x256
    const int row0 = bm * 128, col0 = bn * 256;

    const __hip_bfloat16* A = g.A[seg];
    const __hip_bfloat16* W = g.W[seg];

    // --- staging source mapping (linear LDS dest, inverse-swizzled source) ---
    const int s_line = tid >> 3, s_gr = tid & 7;
    const int glin  = s_gr ^ (s_line & 7);
    const int s_row = (s_line << 1) + (glin >> 2);
    const int s_ks  = glin & 3;
    const __hip_bfloat16* gA = A + (size_t)(row0 + s_row) * E_DIM + s_ks * 8;
    const __hip_bfloat16* gB = W + (size_t)(col0 + s_row) * E_DIM + s_ks * 8;
    const int stA = wid << 10;                  // wave-uniform LDS byte offset

    // --- swizzled ds_read byte offsets (per lane), +i*1024 per 16-row frag ---
    const int rg   = (((l16 & 1) << 2) | quad) ^ ((l16 >> 1) & 7);
    const int aoff = (wm * 32 + (l16 >> 1)) * 128 + rg * 16;
    const int boff = (wn * 32 + (l16 >> 1)) * 128 + rg * 16;

    f32x4 acc[4][4];
    const f32x4 zero = {0.f, 0.f, 0.f, 0.f};
#pragma unroll
    for (int i = 0; i < 4; i++)
#pragma unroll
        for (int j = 0; j < 4; j++) acc[i][j] = zero;

    auto stage_t = [&](int t) {
        char* b = lds_raw + (t % 3) * 24576;
        const int ko = t * 32;
        stage16(gA + ko, (__hip_bfloat16*)(b + stA), lane);                          // A 8KB
        stage16(gB + ko, (__hip_bfloat16*)(b + 8192 + stA), lane);                   // B lo
        stage16(gB + (size_t)128 * E_DIM + ko, (__hip_bfloat16*)(b + 16384 + stA), lane); // B hi
    };

    auto body = [&](int t, bool stg) {
        __builtin_amdgcn_s_barrier();
        __builtin_amdgcn_sched_barrier(0);
        if (stg) stage_t(t + 2);
        const char* ab = lds_raw + (t % 3) * 24576;
        bf16x8 af[4], bf[4];
#pragma unroll
        for (int i = 0; i < 4; i++) af[i] = load8(ab + aoff + i * 1024);
#pragma unroll
        for (int j = 0; j < 4; j++) bf[j] = load8(ab + 8192 + boff + j * 1024);
        __builtin_amdgcn_s_setprio(1);
#pragma unroll
        for (int i = 0; i < 4; i++)
#pragma unroll
            for (int j = 0; j < 4; j++)
                acc[i][j] = __builtin_amdgcn_mfma_f32_16x16x32_bf16(af[i], bf[j], acc[i][j], 0, 0, 0);
        __builtin_amdgcn_s_setprio(0);
        __builtin_amdgcn_sched_barrier(0);
    };

    const int NT = E_DIM / 32;                  // 32 K-tiles
    stage_t(0); stage_t(1);
    for (int t = 0; t < NT - 2; ++t) {
        asm volatile("s_waitcnt vmcnt(3)" ::: "memory");   // tile t's 3 loads landed
        body(t, true);
    }
    asm volatile("s_waitcnt vmcnt(3)" ::: "memory"); body(NT - 2, false);
    asm volatile("s_waitcnt vmcnt(0)" ::: "memory"); body(NT - 1, false);

    // ---- epilogue ----
    const int   mode  = g.mode[seg];
    const float scale = g.scale[seg];
    const float* bias = g.bias[seg];
    void* Cout        = g.C[seg];
#pragma unroll
    for (int j = 0; j < 4; j++) {
        const int col = col0 + wn * 64 + j * 16 + l16;
        const float bv = bias[col];
#pragma unroll
        for (int i = 0; i < 4; i++) {
            const int row = row0 + wm * 64 + i * 16 + quad * 4;
            if (mode == 3) {
                __attribute__((aligned(8))) __hip_bfloat16 o[4];
#pragma unroll
                for (int r = 0; r < 4; r++) o[r] = __float2bfloat16((acc[i][j][r] + bv) * scale);
                const int b_ = row >> 11, s_ = row & 2047, h_ = col >> 6, d_ = col & 63;
                *reinterpret_cast<uint2*>((__hip_bfloat16*)Cout +
                    (((size_t)(b_ * H_NUM + h_)) << 17) + (d_ << 11) + s_) =
                    *reinterpret_cast<uint2*>(o);
            } else {
#pragma unroll
                for (int r = 0; r < 4; r++) {
                    const float v = (acc[i][j][r] + bv) * scale;
                    const int rr = row + r;
                    if (mode == 0) {
                        ((__hip_bfloat16*)Cout)[(size_t)rr * E_DIM + col] = __float2bfloat16(v);
                    } else if (mode == 1) {
                        ((float*)Cout)[(size_t)rr * E_DIM + col] = v;
                    } else {
                        const int b_ = rr >> 11, s_ = rr & 2047, h_ = col >> 6, d_ = col & 63;
                        ((__hip_bfloat16*)Cout)[(((size_t)(b_ * H_NUM + h_)) << 17) + (s_ << 6) + d_] =
                            __float2bfloat16(v);
                    }
                }
            }
        }
    }
}

// ---------------------------------------------------------------------------
// Flash attention v6: split-KV on the R11-measured structure (P LDS
// round-trip RESTORED — v5b's shfl/bpermute replacement measured -30us).
// 512 blocks x 512 threads = 8 waves: waves 0-3 own 64 q-rows each over keys
// [0,1024); waves 4-7 the SAME rows over [1024,2048).  Chain work per chunk
// per wave is UNCHANGED (4 qt x 64 rows; R2's failure was halving it);
// iterations halve, chains/SIMD double (2 -> 4), occupancy cap 25% -> 50%.
// Each 4-wave group stages its OWN K/V double-buffer (R7/R11 pattern).
// No-max exp2 softmax => split is EXACT: o_acc/lsum merged by plain adds via
// a 5KB LDS buffer in 16 (qt,dj) phases.  NO launch_bounds min-waves spec
// (R4's failure was the 64-VGPR corset, not the structure).
// LDS: Pls 40KB + K/V 32KB + Mb 5KB = 77KB -> 2 blocks/CU.
// ---------------------------------------------------------------------------
__global__ __launch_bounds__(512) void attn(const __hip_bfloat16* __restrict__ Qt,
                                            const __hip_bfloat16* __restrict__ Kt,
                                            const __hip_bfloat16* __restrict__ Vt,
                                            __hip_bfloat16* __restrict__ Op)
{
    __shared__ __hip_bfloat16 Pls[8][64][40];                                      // 40 KB
    __shared__ __attribute__((aligned(16))) __hip_bfloat16 Kls[2][2][32 * 64];     // 16 KB
    __shared__ __attribute__((aligned(16))) __hip_bfloat16 Vls[2][2][64 * 32];     // 16 KB
    __shared__ __attribute__((aligned(16))) float Mb[1280];                        //  5 KB

    const int x = blockIdx.x;                   // 512 blocks
    const int bh     = (x & 7) * 8 + ((x >> 3) & 7);   // bh pinned to one XCD
    const int qchunk = x >> 6;                  // 0..7, 256 q-rows each
    const int tid = threadIdx.x;
    const int wave = tid >> 6, lane = tid & 63;
    const int quad = lane >> 4, l16 = lane & 15;
    const int rw = wave & 3, kshalf = wave >> 2;
    const int qrow0 = qchunk * 256 + rw * 64;
    const int kvbase = kshalf << 10;            // 0 or 1024

    const __hip_bfloat16* qb = Qt + ((size_t)bh << 17);
    const __hip_bfloat16* kb = Kt + ((size_t)bh << 17);
    const __hip_bfloat16* vb = Vt + ((size_t)bh << 17);
    __hip_bfloat16* pw = &Pls[wave][0][0];

    // ---- staging source mapping (pre-swizzled, R7-verified), per group ----
    const int rt = tid & 255;                   // position within 4-wave group
    const int skey = rt >> 3, sgk = (rt & 7) ^ (skey & 7);
    const __hip_bfloat16* kSrc = kb + ((kvbase + skey) << 6) + (sgk << 3);
    const int sd = rt >> 2, sgv = (rt & 3) ^ ((sd >> 1) & 3);
    const __hip_bfloat16* vSrc = vb + ((size_t)sd << 11) + (sgv << 3) + kvbase;
    const int stW = rw << 10;                   // slice within the group's 4KB tile

    // swizzle keys for the read side
    const int ksw = l16 & 7, vsw = (l16 >> 1) & 3;

    // Q fragments: 4 q-tiles x 2 d-halves (B-operand layout), held all kernel.
    bf16x8 qf[4][2];
#pragma unroll
    for (int qt = 0; qt < 4; qt++) {
        qf[qt][0] = load8(qb + ((qrow0 + qt * 16 + l16) << 6) + quad * 8);
        qf[qt][1] = load8(qb + ((qrow0 + qt * 16 + l16) << 6) + 32 + quad * 8);
    }

    const f32x4 zero = {0.f, 0.f, 0.f, 0.f};
    f32x4 o_acc[4][4];
#pragma unroll
    for (int qt = 0; qt < 4; qt++)
#pragma unroll
        for (int dj = 0; dj < 4; dj++) o_acc[qt][dj] = zero;
    float lsum[4] = {0.f, 0.f, 0.f, 0.f};

    auto stageKV = [&](int kv, int b) {
        stage16(kSrc + (kv << 6), (__hip_bfloat16*)((char*)&Kls[kshalf][b][0] + stW), lane);
        stage16(vSrc + kv,        (__hip_bfloat16*)((char*)&Vls[kshalf][b][0] + stW), lane);
    };

    auto compute = [&](int b) {
        const char* Kbuf = (const char*)&Kls[kshalf][b][0];
        const char* Vbuf = (const char*)&Vls[kshalf][b][0];
        // ---- S^T = K·Q^T for 2 key-tiles; p = exp2(s); pack to P ----
#pragma unroll
        for (int t = 0; t < 2; t++) {
            const bf16x8 ka = load8(Kbuf + ((t * 16 + l16) << 7) + ((quad ^ ksw) << 4));
            const bf16x8 kc = load8(Kbuf + ((t * 16 + l16) << 7) + (((quad + 4) ^ ksw) << 4));
#pragma unroll
            for (int qt = 0; qt < 4; qt++) {
                f32x4 st = __builtin_amdgcn_mfma_f32_16x16x32_bf16(ka, qf[qt][0], zero, 0, 0, 0);
                st       = __builtin_amdgcn_mfma_f32_16x16x32_bf16(kc, qf[qt][1], st, 0, 0, 0);
                const float p0 = EXP2F(st[0]), p1 = EXP2F(st[1]);
                const float p2 = EXP2F(st[2]), p3 = EXP2F(st[3]);
                lsum[qt] += (p0 + p1) + (p2 + p3);
                const unsigned u0 = (unsigned)__bfloat16_as_ushort(__float2bfloat16(p0));
                const unsigned u1 = (unsigned)__bfloat16_as_ushort(__float2bfloat16(p1));
                const unsigned u2 = (unsigned)__bfloat16_as_ushort(__float2bfloat16(p2));
                const unsigned u3 = (unsigned)__bfloat16_as_ushort(__float2bfloat16(p3));
                uint2 w;
                w.x = (u1 << 16) | u0;
                w.y = (u3 << 16) | u2;
                *reinterpret_cast<uint2*>(&pw[(qt * 16 + l16) * 40 + t * 16 + quad * 4]) = w;
            }
        }
        // ---- O += P·V ----
        bf16x8 vf[4];
#pragma unroll
        for (int dj = 0; dj < 4; dj++)
            vf[dj] = load8(Vbuf + ((dj * 16 + l16) << 6) + ((quad ^ vsw) << 4));
        __builtin_amdgcn_s_setprio(1);
#pragma unroll
        for (int qt = 0; qt < 4; qt++) {
            const bf16x8 pa = load8(&pw[(qt * 16 + l16) * 40 + quad * 8]);
#pragma unroll
            for (int dj = 0; dj < 4; dj++)
                o_acc[qt][dj] = __builtin_amdgcn_mfma_f32_16x16x32_bf16(pa, vf[dj], o_acc[qt][dj], 0, 0, 0);
        }
        __builtin_amdgcn_s_setprio(0);
    };

    stageKV(0, 0);
    int cur = 0;
    for (int kv0 = 0; kv0 < 1024; kv0 += 32) {  // each group walks its half
        __syncthreads();                        // staged buf[cur] landed; prev reads done
        if (kv0 + 32 < 1024) stageKV(kv0 + 32, cur ^ 1);
        compute(cur);
        cur ^= 1;
    }

    // ---- split-KV merge (EXACT: plain sums).  16 phases of 4KB via Mb. ----
#pragma unroll
    for (int qt = 0; qt < 4; qt++) {
#pragma unroll
        for (int dj = 0; dj < 4; dj++) {
            if (kshalf == 1) {
                *reinterpret_cast<f32x4*>(&Mb[(rw * 64 + lane) * 4]) = o_acc[qt][dj];
                if (dj == 0) Mb[1024 + rw * 64 + lane] = lsum[qt];
            }
            __syncthreads();
            if (kshalf == 0) {
                const f32x4 v = *reinterpret_cast<const f32x4*>(&Mb[(rw * 64 + lane) * 4]);
                o_acc[qt][dj] += v;
                if (dj == 0) lsum[qt] += Mb[1024 + rw * 64 + lane];
            }
            __syncthreads();
        }
    }
    if (kshalf == 1) return;

    // ---- epilogue (waves 0-3): reduce l across quads, write C-layout rows ----
    const int b_ = bh >> 4, h_ = bh & 15;
#pragma unroll
    for (int qt = 0; qt < 4; qt++) {
        float l = lsum[qt];
        l += __shfl_xor(l, 16, 64);
        l += __shfl_xor(l, 32, 64);
#pragma unroll
        for (int r = 0; r < 4; r++) {
            const float lr = __shfl(l, quad * 4 + r, 64);   // l of q-row qt*16+quad*4+r
            const float inv = 1.f / lr;
            const size_t ro = ((size_t)b_ * S_LEN + (qrow0 + qt * 16 + quad * 4 + r)) * E_DIM + h_ * D_DIM;
#pragma unroll
            for (int dj = 0; dj < 4; dj++)
                Op[ro + dj * 16 + l16] = __float2bfloat16(o_acc[qt][dj][r] * inv);
        }
    }
}

// ---------------------------------------------------------------------------
extern "C" void kernel_launch(void* const* d_in, const int* in_sizes, int n_in,
                              void* d_out, int out_size, void* d_ws, size_t ws_size,
                              hipStream_t stream)
{
    const float* Qf  = (const float*)d_in[0];
    const float* Kf  = (const float*)d_in[1];
    const float* Vf  = (const float*)d_in[2];
    const float* Wqf = (const float*)d_in[3];
    const float* bqf = (const float*)d_in[4];
    const float* Wkf = (const float*)d_in[5];
    const float* bkf = (const float*)d_in[6];
    const float* Wvf = (const float*)d_in[7];
    const float* bvf = (const float*)d_in[8];
    const float* Wof = (const float*)d_in[9];
    const float* bof = (const float*)d_in[10];

    const size_t n_act = (size_t)M_ROWS * E_DIM;   // 8,388,608
    const size_t n_w   = (size_t)E_DIM * E_DIM;    // 1,048,576

    const dim3 blk(256), gblk(512), ablk(512);
    const int cg_act = (int)(n_act / 8 / 256);
    const int cg_w   = (int)(n_w / 8 / 256);

    const size_t need_fast = (6 * n_act + 4 * n_w) * sizeof(__hip_bfloat16);  // 104 MB

    if (ws_size >= need_fast) {
        // ---- fast path: 4 dispatches total ----
        __hip_bfloat16* Xq = (__hip_bfloat16*)d_ws;
        __hip_bfloat16* Xk = Xq + n_act;
        __hip_bfloat16* Xv = Xk + n_act;
        __hip_bfloat16* Wb = Xv + n_act;           // 4 weights back-to-back
        __hip_bfloat16* Qt = Wb + 4 * n_w;
        __hip_bfloat16* Kt = Qt + n_act;
        __hip_bfloat16* Vt = Kt + n_act;

        // 1) all conversions in one launch (~33us)
        CvtArgs ca;
        ca.s[0] = Qf;  ca.s[1] = Kf;  ca.s[2] = Vf;
        ca.s[3] = Wqf; ca.s[4] = Wkf; ca.s[5] = Wvf; ca.s[6] = Wof;
        ca.d[0] = Xq;  ca.d[1] = Xk;  ca.d[2] = Xv;
        ca.d[3] = Wb;  ca.d[4] = Wb + n_w; ca.d[5] = Wb + 2 * n_w; ca.d[6] = Wb + 3 * n_w;
        cvt_all<<<dim3(N8TOT / 256), blk, 0, stream>>>(ca);

        // 2) QKV projections co-launched (R7/R11-measured ~76us)
        GemmArgs qkv;
        qkv.A[0] = Xq;  qkv.A[1] = Xk;  qkv.A[2] = Xv;
        qkv.W[0] = Wb;  qkv.W[1] = Wb + n_w;  qkv.W[2] = Wb + 2*n_w;
        qkv.bias[0] = bqf;  qkv.bias[1] = bkf;  qkv.bias[2] = bvf;
        qkv.C[0] = Qt;  qkv.C[1] = Kt;  qkv.C[2] = Vt;
        qkv.scale[0] = QK_SCALE;  qkv.scale[1] = 1.0f;  qkv.scale[2] = 1.0f;
        qkv.mode[0] = 2;  qkv.mode[1] = 2;  qkv.mode[2] = 3;
        gemm_bt<<<dim3(768), gblk, 0, stream>>>(qkv);

        // 3) attention -> Xq (v6: split-KV, 512 blocks x 8 waves)
        attn<<<dim3(512), ablk, 0, stream>>>(Qt, Kt, Vt, Xq);

        // 4) output projection (R5/R7/R11-measured ~48us)
        GemmArgs og;
        og.A[0] = Xq;  og.A[1] = Xq;  og.A[2] = Xq;
        og.W[0] = Wb + 3*n_w;  og.W[1] = og.W[0];  og.W[2] = og.W[0];
        og.bias[0] = bof;  og.bias[1] = bof;  og.bias[2] = bof;
        og.C[0] = d_out;  og.C[1] = d_out;  og.C[2] = d_out;
        og.scale[0] = 1.0f;  og.scale[1] = 1.0f;  og.scale[2] = 1.0f;
        og.mode[0] = 1;  og.mode[1] = 1;  og.mode[2] = 1;
        gemm_bt<<<dim3(256), gblk, 0, stream>>>(og);
    } else {
        // ---- fallback: sequential, shared X/Wb buffers (66 MB) ----
        __hip_bfloat16* X  = (__hip_bfloat16*)d_ws;
        __hip_bfloat16* Wb = X + n_act;
        __hip_bfloat16* Qt = Wb + n_w;
        __hip_bfloat16* Kt = Qt + n_act;
        __hip_bfloat16* Vt = Kt + n_act;

        auto one = [&](const float* Af, const float* Wf, const float* bf_,
                       void* C, float sc, int md) {
            cvt_f32_bf16<<<cg_act, blk, 0, stream>>>(Af, X, (int)(n_act / 8));
            cvt_f32_bf16<<<cg_w,   blk, 0, stream>>>(Wf, Wb, (int)(n_w / 8));
            GemmArgs a;
            a.A[0] = X; a.A[1] = X; a.A[2] = X;
            a.W[0] = Wb; a.W[1] = Wb; a.W[2] = Wb;
            a.bias[0] = bf_; a.bias[1] = bf_; a.bias[2] = bf_;
            a.C[0] = C; a.C[1] = C; a.C[2] = C;
            a.scale[0] = sc; a.scale[1] = sc; a.scale[2] = sc;
            a.mode[0] = md; a.mode[1] = md; a.mode[2] = md;
            gemm_bt<<<dim3(256), gblk, 0, stream>>>(a);
        };
        one(Qf, Wqf, bqf, Qt, QK_SCALE, 2);
        one(Kf, Wkf, bkf, Kt, 1.0f, 2);
        one(Vf, Wvf, bvf, Vt, 1.0f, 3);
        attn<<<dim3(512), ablk, 0, stream>>>(Qt, Kt, Vt, X);
        cvt_f32_bf16<<<cg_w, blk, 0, stream>>>(Wof, Wb, (int)(n_w / 8));
        GemmArgs og;
        og.A[0] = X; og.A[1] = X; og.A[2] = X;
        og.W[0] = Wb; og.W[1] = Wb; og.W[2] = Wb;
        og.bias[0] = bof; og.bias[1] = bof; og.bias[2] = bof;
        og.C[0] = d_out; og.C[1] = d_out; og.C[2] = d_out;
        og.scale[0] = 1.0f; og.scale[1] = 1.0f; og.scale[2] = 1.0f;
        og.mode[0] = 1; og.mode[1] = 1; og.mode[2] = 1;
        gemm_bt<<<dim3(256), gblk, 0, stream>>>(og);
    }
}

// Round 16
// 325.237 us; speedup vs baseline: 1.1585x; 1.1319x over previous
//
#include <hip/hip_runtime.h>
#include <hip/hip_bf16.h>

// Problem constants
#define B_SZ   4
#define S_LEN  2048
#define E_DIM  1024
#define H_NUM  16
#define D_DIM  64
#define M_ROWS (B_SZ * S_LEN)            // 8192
#define QK_SCALE 0.1803368801111204f     // (1/sqrt(64)) * log2(e): softmax in exp2 domain

typedef __attribute__((ext_vector_type(8))) __bf16 bf16x8;
typedef __attribute__((ext_vector_type(4))) float  f32x4;

__device__ __forceinline__ bf16x8 load8(const void* p) {
    return __builtin_bit_cast(bf16x8, *reinterpret_cast<const uint4*>(p));
}

#if defined(__has_builtin)
#if __has_builtin(__builtin_amdgcn_exp2f)
#define EXP2F(x) __builtin_amdgcn_exp2f(x)
#endif
#if __has_builtin(__builtin_amdgcn_global_load_lds)
#define HAVE_GLL 1
#endif
#endif
#ifndef EXP2F
#define EXP2F(x) exp2f(x)
#endif

// 16B-per-lane global->LDS stage (wave-uniform LDS base, lane i -> base+16i).
__device__ __forceinline__ void stage16(const __hip_bfloat16* g, __hip_bfloat16* lbase, int lane) {
#ifdef HAVE_GLL
    __builtin_amdgcn_global_load_lds((const __attribute__((address_space(1))) unsigned int*)g,
                                     (__attribute__((address_space(3))) unsigned int*)lbase,
                                     16, 0, 0);
#else
    reinterpret_cast<uint4*>(lbase)[lane] = *reinterpret_cast<const uint4*>(g);
#endif
}

// ---------------------------------------------------------------------------
// Fused f32 -> bf16 convert for ALL 7 tensors in ONE dispatch (~30us).
// ---------------------------------------------------------------------------
#define N8A (1 << 20)
#define N8W (1 << 17)
#define N8TOT (3 * N8A + 4 * N8W)

struct CvtArgs {
    const float* s[7];
    __hip_bfloat16* d[7];
};

__global__ __launch_bounds__(256) void cvt_all(CvtArgs a)
{
    const int i = blockIdx.x * 256 + threadIdx.x;
    if (i >= N8TOT) return;
    int seg, off;
    if (i < 3 * N8A) { seg = i >> 20;              off = i & (N8A - 1); }
    else             { const int j = i - 3 * N8A;
                       seg = 3 + (j >> 17);        off = j & (N8W - 1); }
    const float* s = a.s[seg];
    __hip_bfloat16* d = a.d[seg];
    const float4 x = reinterpret_cast<const float4*>(s)[off * 2];
    const float4 y = reinterpret_cast<const float4*>(s)[off * 2 + 1];
    __hip_bfloat16 o[8];
    o[0] = __float2bfloat16(x.x); o[1] = __float2bfloat16(x.y);
    o[2] = __float2bfloat16(x.z); o[3] = __float2bfloat16(x.w);
    o[4] = __float2bfloat16(y.x); o[5] = __float2bfloat16(y.y);
    o[6] = __float2bfloat16(y.z); o[7] = __float2bfloat16(y.w);
    reinterpret_cast<uint4*>(d)[off] = *reinterpret_cast<uint4*>(o);
}

// single-tensor cvt kept for the fallback path
__global__ __launch_bounds__(256) void cvt_f32_bf16(const float* __restrict__ s,
                                                    __hip_bfloat16* __restrict__ d,
                                                    int n8)
{
    const int i = blockIdx.x * 256 + threadIdx.x;
    if (i >= n8) return;
    const float4 a = reinterpret_cast<const float4*>(s)[i * 2];
    const float4 b = reinterpret_cast<const float4*>(s)[i * 2 + 1];
    __hip_bfloat16 o[8];
    o[0] = __float2bfloat16(a.x); o[1] = __float2bfloat16(a.y);
    o[2] = __float2bfloat16(a.z); o[3] = __float2bfloat16(a.w);
    o[4] = __float2bfloat16(b.x); o[5] = __float2bfloat16(b.y);
    o[6] = __float2bfloat16(b.z); o[7] = __float2bfloat16(b.w);
    reinterpret_cast<uint4*>(d)[i] = *reinterpret_cast<uint4*>(o);
}

// ---------------------------------------------------------------------------
// Pipelined GEMM (R5/R7/R11-measured, verbatim): C = A @ W^T + bias.
// BM=128, BN=256, BK=32, K=1024.  512 threads = 8 waves, 64x64 out/wave.
// 3-buffer LDS ring (72KB) -> 2 blocks/CU; prefetch distance 2; vmcnt(3).
// QKV: 768 blocks (~76us).  OG: 256 blocks (~48us).
// ---------------------------------------------------------------------------
struct GemmArgs {
    const __hip_bfloat16* A[3];
    const __hip_bfloat16* W[3];
    const float* bias[3];
    void* C[3];
    float scale[3];
    int mode[3];
};

__global__ __launch_bounds__(512, 4) void gemm_bt(GemmArgs g)
{
    __shared__ __attribute__((aligned(16))) char lds_raw[3 * 24576];   // 72 KB ring

    const int tid = threadIdx.x;
    const int wid = tid >> 6, lane = tid & 63;
    const int quad = lane >> 4, l16 = lane & 15;
    const int wm = wid >> 2, wn = wid & 3;

    const int seg = blockIdx.x >> 8;
    int bid = blockIdx.x & 255;
    bid = (bid & 7) * 32 + (bid >> 3);          // XCD-aware swizzle (bijective, 256 wg)
    const int bm = bid >> 2, bn = bid & 3;      // 64 x 4 tiles of 128x256
    const int row0 = bm * 128, col0 = bn * 256;

    const __hip_bfloat16* A = g.A[seg];
    const __hip_bfloat16* W = g.W[seg];

    // --- staging source mapping (linear LDS dest, inverse-swizzled source) ---
    const int s_line = tid >> 3, s_gr = tid & 7;
    const int glin  = s_gr ^ (s_line & 7);
    const int s_row = (s_line << 1) + (glin >> 2);
    const int s_ks  = glin & 3;
    const __hip_bfloat16* gA = A + (size_t)(row0 + s_row) * E_DIM + s_ks * 8;
    const __hip_bfloat16* gB = W + (size_t)(col0 + s_row) * E_DIM + s_ks * 8;
    const int stA = wid << 10;                  // wave-uniform LDS byte offset

    // --- swizzled ds_read byte offsets (per lane), +i*1024 per 16-row frag ---
    const int rg   = (((l16 & 1) << 2) | quad) ^ ((l16 >> 1) & 7);
    const int aoff = (wm * 32 + (l16 >> 1)) * 128 + rg * 16;
    const int boff = (wn * 32 + (l16 >> 1)) * 128 + rg * 16;

    f32x4 acc[4][4];
    const f32x4 zero = {0.f, 0.f, 0.f, 0.f};
#pragma unroll
    for (int i = 0; i < 4; i++)
#pragma unroll
        for (int j = 0; j < 4; j++) acc[i][j] = zero;

    auto stage_t = [&](int t) {
        char* b = lds_raw + (t % 3) * 24576;
        const int ko = t * 32;
        stage16(gA + ko, (__hip_bfloat16*)(b + stA), lane);                          // A 8KB
        stage16(gB + ko, (__hip_bfloat16*)(b + 8192 + stA), lane);                   // B lo
        stage16(gB + (size_t)128 * E_DIM + ko, (__hip_bfloat16*)(b + 16384 + stA), lane); // B hi
    };

    auto body = [&](int t, bool stg) {
        __builtin_amdgcn_s_barrier();
        __builtin_amdgcn_sched_barrier(0);
        if (stg) stage_t(t + 2);
        const char* ab = lds_raw + (t % 3) * 24576;
        bf16x8 af[4], bf[4];
#pragma unroll
        for (int i = 0; i < 4; i++) af[i] = load8(ab + aoff + i * 1024);
#pragma unroll
        for (int j = 0; j < 4; j++) bf[j] = load8(ab + 8192 + boff + j * 1024);
        __builtin_amdgcn_s_setprio(1);
#pragma unroll
        for (int i = 0; i < 4; i++)
#pragma unroll
            for (int j = 0; j < 4; j++)
                acc[i][j] = __builtin_amdgcn_mfma_f32_16x16x32_bf16(af[i], bf[j], acc[i][j], 0, 0, 0);
        __builtin_amdgcn_s_setprio(0);
        __builtin_amdgcn_sched_barrier(0);
    };

    const int NT = E_DIM / 32;                  // 32 K-tiles
    stage_t(0); stage_t(1);
    for (int t = 0; t < NT - 2; ++t) {
        asm volatile("s_waitcnt vmcnt(3)" ::: "memory");   // tile t's 3 loads landed
        body(t, true);
    }
    asm volatile("s_waitcnt vmcnt(3)" ::: "memory"); body(NT - 2, false);
    asm volatile("s_waitcnt vmcnt(0)" ::: "memory"); body(NT - 1, false);

    // ---- epilogue ----
    const int   mode  = g.mode[seg];
    const float scale = g.scale[seg];
    const float* bias = g.bias[seg];
    void* Cout        = g.C[seg];
#pragma unroll
    for (int j = 0; j < 4; j++) {
        const int col = col0 + wn * 64 + j * 16 + l16;
        const float bv = bias[col];
#pragma unroll
        for (int i = 0; i < 4; i++) {
            const int row = row0 + wm * 64 + i * 16 + quad * 4;
            if (mode == 3) {
                __attribute__((aligned(8))) __hip_bfloat16 o[4];
#pragma unroll
                for (int r = 0; r < 4; r++) o[r] = __float2bfloat16((acc[i][j][r] + bv) * scale);
                const int b_ = row >> 11, s_ = row & 2047, h_ = col >> 6, d_ = col & 63;
                *reinterpret_cast<uint2*>((__hip_bfloat16*)Cout +
                    (((size_t)(b_ * H_NUM + h_)) << 17) + (d_ << 11) + s_) =
                    *reinterpret_cast<uint2*>(o);
            } else {
#pragma unroll
                for (int r = 0; r < 4; r++) {
                    const float v = (acc[i][j][r] + bv) * scale;
                    const int rr = row + r;
                    if (mode == 0) {
                        ((__hip_bfloat16*)Cout)[(size_t)rr * E_DIM + col] = __float2bfloat16(v);
                    } else if (mode == 1) {
                        ((float*)Cout)[(size_t)rr * E_DIM + col] = v;
                    } else {
                        const int b_ = rr >> 11, s_ = rr & 2047, h_ = col >> 6, d_ = col & 63;
                        ((__hip_bfloat16*)Cout)[(((size_t)(b_ * H_NUM + h_)) << 17) + (s_ << 6) + d_] =
                            __float2bfloat16(v);
                    }
                }
            }
        }
    }
}

// ---------------------------------------------------------------------------
// Flash attention (R11-measured, 96.5us x5): 256 blocks x 512 threads = 8
// waves; each block owns 512 q-rows of one bh; K/V LDS tiles staged ONCE per
// block and shared by 8 waves (KV traffic 134MB).  Threads 0-255 stage K,
// 256-511 stage V.  Double-buffered, XOR-swizzled both-sides; S^T trick;
// no-max exp2 softmax; bh->XCD pinning; setprio on PV.
// LDS: P 40KB + K/V 16KB = 56KB.
// ---------------------------------------------------------------------------
__global__ __launch_bounds__(512) void attn(const __hip_bfloat16* __restrict__ Qt,
                                            const __hip_bfloat16* __restrict__ Kt,
                                            const __hip_bfloat16* __restrict__ Vt,
                                            __hip_bfloat16* __restrict__ Op)
{
    __shared__ __hip_bfloat16 Pls[8][64][40];                                   // 40 KB
    __shared__ __attribute__((aligned(16))) __hip_bfloat16 Kls[2][32 * 64];     //  8 KB
    __shared__ __attribute__((aligned(16))) __hip_bfloat16 Vls[2][64 * 32];     //  8 KB

    const int x = blockIdx.x;                   // 256 blocks
    const int bh     = (x & 7) * 8 + ((x >> 3) & 7);   // bh's 4 blocks share an XCD
    const int qchunk = x >> 6;                  // 0..3, 512 q-rows each
    const int tid = threadIdx.x;
    const int wave = tid >> 6, lane = tid & 63;
    const int quad = lane >> 4, l16 = lane & 15;
    const int qrow0 = qchunk * 512 + wave * 64;

    const __hip_bfloat16* qb = Qt + ((size_t)bh << 17);
    const __hip_bfloat16* kb = Kt + ((size_t)bh << 17);
    const __hip_bfloat16* vb = Vt + ((size_t)bh << 17);
    __hip_bfloat16* pw = &Pls[wave][0][0];

    // ---- staging roles: threads 0-255 stage K, 256-511 stage V ----
    const int rt = tid & 255;
    const int skey = rt >> 3, sgk = (rt & 7) ^ (skey & 7);
    const __hip_bfloat16* kSrc = kb + (skey << 6) + (sgk << 3);
    const int sd = rt >> 2, sgv = (rt & 3) ^ ((sd >> 1) & 3);
    const __hip_bfloat16* vSrc = vb + ((size_t)sd << 11) + (sgv << 3);
    const int stW = (wave & 3) << 10;           // slice within the 4KB tile

    // swizzle keys for the read side
    const int ksw = l16 & 7, vsw = (l16 >> 1) & 3;

    // Q fragments: 4 q-tiles x 2 d-halves (B-operand layout), held all kernel.
    bf16x8 qf[4][2];
#pragma unroll
    for (int qt = 0; qt < 4; qt++) {
        qf[qt][0] = load8(qb + ((qrow0 + qt * 16 + l16) << 6) + quad * 8);
        qf[qt][1] = load8(qb + ((qrow0 + qt * 16 + l16) << 6) + 32 + quad * 8);
    }

    const f32x4 zero = {0.f, 0.f, 0.f, 0.f};
    f32x4 o_acc[4][4];
#pragma unroll
    for (int qt = 0; qt < 4; qt++)
#pragma unroll
        for (int dj = 0; dj < 4; dj++) o_acc[qt][dj] = zero;
    float lsum[4] = {0.f, 0.f, 0.f, 0.f};

    auto stageKV = [&](int kv, int b) {
        if (tid < 256)
            stage16(kSrc + (kv << 6), (__hip_bfloat16*)((char*)&Kls[b][0] + stW), lane);
        else
            stage16(vSrc + kv,        (__hip_bfloat16*)((char*)&Vls[b][0] + stW), lane);
    };

    auto compute = [&](int b) {
        const char* Kbuf = (const char*)&Kls[b][0];
        const char* Vbuf = (const char*)&Vls[b][0];
#pragma unroll
        for (int t = 0; t < 2; t++) {
            const bf16x8 ka = load8(Kbuf + ((t * 16 + l16) << 7) + ((quad ^ ksw) << 4));
            const bf16x8 kc = load8(Kbuf + ((t * 16 + l16) << 7) + (((quad + 4) ^ ksw) << 4));
#pragma unroll
            for (int qt = 0; qt < 4; qt++) {
                f32x4 st = __builtin_amdgcn_mfma_f32_16x16x32_bf16(ka, qf[qt][0], zero, 0, 0, 0);
                st       = __builtin_amdgcn_mfma_f32_16x16x32_bf16(kc, qf[qt][1], st, 0, 0, 0);
                const float p0 = EXP2F(st[0]), p1 = EXP2F(st[1]);
                const float p2 = EXP2F(st[2]), p3 = EXP2F(st[3]);
                lsum[qt] += (p0 + p1) + (p2 + p3);
                const unsigned u0 = (unsigned)__bfloat16_as_ushort(__float2bfloat16(p0));
                const unsigned u1 = (unsigned)__bfloat16_as_ushort(__float2bfloat16(p1));
                const unsigned u2 = (unsigned)__bfloat16_as_ushort(__float2bfloat16(p2));
                const unsigned u3 = (unsigned)__bfloat16_as_ushort(__float2bfloat16(p3));
                uint2 w;
                w.x = (u1 << 16) | u0;
                w.y = (u3 << 16) | u2;
                *reinterpret_cast<uint2*>(&pw[(qt * 16 + l16) * 40 + t * 16 + quad * 4]) = w;
            }
        }
        bf16x8 vf[4];
#pragma unroll
        for (int dj = 0; dj < 4; dj++)
            vf[dj] = load8(Vbuf + ((dj * 16 + l16) << 6) + ((quad ^ vsw) << 4));
        __builtin_amdgcn_s_setprio(1);
#pragma unroll
        for (int qt = 0; qt < 4; qt++) {
            const bf16x8 pa = load8(&pw[(qt * 16 + l16) * 40 + quad * 8]);
#pragma unroll
            for (int dj = 0; dj < 4; dj++)
                o_acc[qt][dj] = __builtin_amdgcn_mfma_f32_16x16x32_bf16(pa, vf[dj], o_acc[qt][dj], 0, 0, 0);
        }
        __builtin_amdgcn_s_setprio(0);
    };

    stageKV(0, 0);
    int cur = 0;
    for (int kv0 = 0; kv0 < S_LEN; kv0 += 32) {
        __syncthreads();                        // staged buf[cur] landed; prev reads done
        if (kv0 + 32 < S_LEN) stageKV(kv0 + 32, cur ^ 1);
        compute(cur);
        cur ^= 1;
    }

    // ---- epilogue: reduce l across quads, redistribute to C-layout rows ----
    const int b_ = bh >> 4, h_ = bh & 15;
#pragma unroll
    for (int qt = 0; qt < 4; qt++) {
        float l = lsum[qt];
        l += __shfl_xor(l, 16, 64);
        l += __shfl_xor(l, 32, 64);
#pragma unroll
        for (int r = 0; r < 4; r++) {
            const float lr = __shfl(l, quad * 4 + r, 64);   // l of q-row qt*16+quad*4+r
            const float inv = 1.f / lr;
            const size_t ro = ((size_t)b_ * S_LEN + (qrow0 + qt * 16 + quad * 4 + r)) * E_DIM + h_ * D_DIM;
#pragma unroll
            for (int dj = 0; dj < 4; dj++)
                Op[ro + dj * 16 + l16] = __float2bfloat16(o_acc[qt][dj][r] * inv);
        }
    }
}

// ---------------------------------------------------------------------------
extern "C" void kernel_launch(void* const* d_in, const int* in_sizes, int n_in,
                              void* d_out, int out_size, void* d_ws, size_t ws_size,
                              hipStream_t stream)
{
    const float* Qf  = (const float*)d_in[0];
    const float* Kf  = (const float*)d_in[1];
    const float* Vf  = (const float*)d_in[2];
    const float* Wqf = (const float*)d_in[3];
    const float* bqf = (const float*)d_in[4];
    const float* Wkf = (const float*)d_in[5];
    const float* bkf = (const float*)d_in[6];
    const float* Wvf = (const float*)d_in[7];
    const float* bvf = (const float*)d_in[8];
    const float* Wof = (const float*)d_in[9];
    const float* bof = (const float*)d_in[10];

    const size_t n_act = (size_t)M_ROWS * E_DIM;   // 8,388,608
    const size_t n_w   = (size_t)E_DIM * E_DIM;    // 1,048,576

    const dim3 blk(256), gblk(512), ablk(512);
    const int cg_act = (int)(n_act / 8 / 256);
    const int cg_w   = (int)(n_w / 8 / 256);

    const size_t need_fast = (6 * n_act + 4 * n_w) * sizeof(__hip_bfloat16);  // 104 MB

    if (ws_size >= need_fast) {
        // ---- fast path: 4 dispatches total ----
        __hip_bfloat16* Xq = (__hip_bfloat16*)d_ws;
        __hip_bfloat16* Xk = Xq + n_act;
        __hip_bfloat16* Xv = Xk + n_act;
        __hip_bfloat16* Wb = Xv + n_act;           // 4 weights back-to-back
        __hip_bfloat16* Qt = Wb + 4 * n_w;
        __hip_bfloat16* Kt = Qt + n_act;
        __hip_bfloat16* Vt = Kt + n_act;

        // 1) all conversions in one launch (~30us)
        CvtArgs ca;
        ca.s[0] = Qf;  ca.s[1] = Kf;  ca.s[2] = Vf;
        ca.s[3] = Wqf; ca.s[4] = Wkf; ca.s[5] = Wvf; ca.s[6] = Wof;
        ca.d[0] = Xq;  ca.d[1] = Xk;  ca.d[2] = Xv;
        ca.d[3] = Wb;  ca.d[4] = Wb + n_w; ca.d[5] = Wb + 2 * n_w; ca.d[6] = Wb + 3 * n_w;
        cvt_all<<<dim3(N8TOT / 256), blk, 0, stream>>>(ca);

        // 2) QKV projections co-launched (R7/R11-measured ~76us)
        GemmArgs qkv;
        qkv.A[0] = Xq;  qkv.A[1] = Xk;  qkv.A[2] = Xv;
        qkv.W[0] = Wb;  qkv.W[1] = Wb + n_w;  qkv.W[2] = Wb + 2*n_w;
        qkv.bias[0] = bqf;  qkv.bias[1] = bkf;  qkv.bias[2] = bvf;
        qkv.C[0] = Qt;  qkv.C[1] = Kt;  qkv.C[2] = Vt;
        qkv.scale[0] = QK_SCALE;  qkv.scale[1] = 1.0f;  qkv.scale[2] = 1.0f;
        qkv.mode[0] = 2;  qkv.mode[1] = 2;  qkv.mode[2] = 3;
        gemm_bt<<<dim3(768), gblk, 0, stream>>>(qkv);

        // 3) attention -> Xq (R11-measured 96.5us, 8-wave shared-KV)
        attn<<<dim3(256), ablk, 0, stream>>>(Qt, Kt, Vt, Xq);

        // 4) output projection (R5/R7/R11-measured ~48us)
        GemmArgs og;
        og.A[0] = Xq;  og.A[1] = Xq;  og.A[2] = Xq;
        og.W[0] = Wb + 3*n_w;  og.W[1] = og.W[0];  og.W[2] = og.W[0];
        og.bias[0] = bof;  og.bias[1] = bof;  og.bias[2] = bof;
        og.C[0] = d_out;  og.C[1] = d_out;  og.C[2] = d_out;
        og.scale[0] = 1.0f;  og.scale[1] = 1.0f;  og.scale[2] = 1.0f;
        og.mode[0] = 1;  og.mode[1] = 1;  og.mode[2] = 1;
        gemm_bt<<<dim3(256), gblk, 0, stream>>>(og);
    } else {
        // ---- fallback: sequential, shared X/Wb buffers (66 MB) ----
        __hip_bfloat16* X  = (__hip_bfloat16*)d_ws;
        __hip_bfloat16* Wb = X + n_act;
        __hip_bfloat16* Qt = Wb + n_w;
        __hip_bfloat16* Kt = Qt + n_act;
        __hip_bfloat16* Vt = Kt + n_act;

        auto one = [&](const float* Af, const float* Wf, const float* bf_,
                       void* C, float sc, int md) {
            cvt_f32_bf16<<<cg_act, blk, 0, stream>>>(Af, X, (int)(n_act / 8));
            cvt_f32_bf16<<<cg_w,   blk, 0, stream>>>(Wf, Wb, (int)(n_w / 8));
            GemmArgs a;
            a.A[0] = X; a.A[1] = X; a.A[2] = X;
            a.W[0] = Wb; a.W[1] = Wb; a.W[2] = Wb;
            a.bias[0] = bf_; a.bias[1] = bf_; a.bias[2] = bf_;
            a.C[0] = C; a.C[1] = C; a.C[2] = C;
            a.scale[0] = sc; a.scale[1] = sc; a.scale[2] = sc;
            a.mode[0] = md; a.mode[1] = md; a.mode[2] = md;
            gemm_bt<<<dim3(256), gblk, 0, stream>>>(a);
        };
        one(Qf, Wqf, bqf, Qt, QK_SCALE, 2);
        one(Kf, Wkf, bkf, Kt, 1.0f, 2);
        one(Vf, Wvf, bvf, Vt, 1.0f, 3);
        attn<<<dim3(256), ablk, 0, stream>>>(Qt, Kt, Vt, X);
        cvt_f32_bf16<<<cg_w, blk, 0, stream>>>(Wof, Wb, (int)(n_w / 8));
        GemmArgs og;
        og.A[0] = X; og.A[1] = X; og.A[2] = X;
        og.W[0] = Wb; og.W[1] = Wb; og.W[2] = Wb;
        og.bias[0] = bof; og.bias[1] = bof; og.bias[2] = bof;
        og.C[0] = d_out; og.C[1] = d_out; og.C[2] = d_out;
        og.scale[0] = 1.0f; og.scale[1] = 1.0f; og.scale[2] = 1.0f;
        og.mode[0] = 1; og.mode[1] = 1; og.mode[2] = 1;
        gemm_bt<<<dim3(256), gblk, 0, stream>>>(og);
    }
}